// Round 4
// baseline (401.966 us; speedup 1.0000x reference)
//
#include <hip/hip_runtime.h>

#define PH_ 7
#define PW_ 7
#define C_ 256
#define H_ 200
#define W_ 272
#define HW_ (H_*W_)
#define CT 8                  // channels per LDS tile
#define NT (C_/CT)            // 32 tiles
#define NBIN (PH_*PW_)        // 49
#define NCOMP (CT*NBIN)       // 392 compute items per tile
#define RMAX 32               // max region rows
#define SMAX 37               // max padded row stride (4*9+1)
#define TILE_F (CT*RMAX*SMAX) // 9472 floats = 37.9 KB
#define NSTG 5                // ceil(max nf4 = 8*32*9 / 512)

__global__ __launch_bounds__(512, 6)
void roialign_kernel(const float* __restrict__ feat,
                     const float* __restrict__ rois,
                     float* __restrict__ out) {
  // yp[2*ph+iy] = {int y0, hy*vy, ly*vy, int y1i}
  // xp[2*pw+ix] = {int c,  wl,    wr,    0}
  __shared__ float4 yp[PH_*2];
  __shared__ float4 xp[PW_*2];
  __shared__ int prm[5];   // base, ymin, xs4, rh, ng4
  __shared__ __align__(16) float tile[TILE_F];

  const int n = blockIdx.x;
  const int tid = threadIdx.x;
  const float* roi = rois + (size_t)n * 5;

  if (tid < 28) {
    float x1 = roi[1] * 0.0625f, y1 = roi[2] * 0.0625f;
    float x2 = roi[3] * 0.0625f, y2 = roi[4] * 0.0625f;
    float roi_w = fmaxf(x2 - x1, 1.0f);
    float roi_h = fmaxf(y2 - y1, 1.0f);
    float bin_w = roi_w * (1.0f / 7.0f);
    float bin_h = roi_h * (1.0f / 7.0f);
    if (tid == 0) prm[0] = (int)roi[0] * (C_ * HW_);
    if (tid < 14) {
      int ph = tid >> 1, iy = tid & 1;
      float y = y1 + (float)ph * bin_h + ((float)iy + 0.5f) * bin_h * 0.5f;
      float v = (y >= -1.0f && y <= (float)H_) ? 1.0f : 0.0f;
      float yc = fminf(fmaxf(y, 0.0f), (float)(H_ - 1));
      int y0 = (int)floorf(yc);
      if (y0 > H_ - 1) y0 = H_ - 1;
      int y1i = min(y0 + 1, H_ - 1);
      float ly = yc - (float)y0;
      float hy = 1.0f - ly;
      yp[tid] = make_float4(__int_as_float(y0), hy * v, ly * v,
                            __int_as_float(y1i));
    } else {
      int t = tid - 14;
      int pw = t >> 1, ix = t & 1;
      float x = x1 + (float)pw * bin_w + ((float)ix + 0.5f) * bin_w * 0.5f;
      float v = (x >= -1.0f && x <= (float)W_) ? 0.25f : 0.0f;
      float xc = fminf(fmaxf(x, 0.0f), (float)(W_ - 1));
      int x0 = (int)floorf(xc);
      float lx = xc - (float)x0;
      float hx = 1.0f - lx;
      int c; float wl, wr;
      if (x0 >= W_ - 1) { c = W_ - 2; wl = 0.0f; wr = hx * v; }
      else              { c = x0;     wl = hx * v; wr = lx * v; }
      xp[t] = make_float4(__int_as_float(c), wl, wr, 0.0f);
    }
  }
  __syncthreads();

  if (tid == 0) {
    int ymin = H_, ymax = 0, cmin = W_, cmax = 0;
#pragma unroll
    for (int i = 0; i < 14; ++i) {
      int y0 = __float_as_int(yp[i].x), y1i = __float_as_int(yp[i].w);
      ymin = min(ymin, y0); ymax = max(ymax, y1i);
      int c = __float_as_int(xp[i].x);
      cmin = min(cmin, c); cmax = max(cmax, c);
    }
    int xs4 = cmin & ~3;
    prm[1] = ymin;
    prm[2] = xs4;
    prm[3] = ymax - ymin + 1;              // rh <= 32
    prm[4] = (cmax + 1 - xs4 + 4) >> 2;    // ng4 <= 9 (never reads past col W-1)
  }
  __syncthreads();

  const int base = prm[0];
  const int ymin = prm[1];
  const int xs4  = prm[2];
  const int rh   = prm[3];
  const int ng4  = prm[4];
  const int rg   = rh * ng4;        // float4s per channel
  const int nf4  = CT * rg;         // float4s per tile
  const int S    = 4 * ng4 + 1;     // odd LDS row stride -> all 32 banks
  const int csz  = rh * S;          // LDS floats per channel

  // ---- hoisted staging descriptors (ROI-constant across all 32 tiles) ----
  int goff[NSTG], loff[NSTG];
  bool vld[NSTG];
#pragma unroll
  for (int i = 0; i < NSTG; ++i) {
    int idx = tid + i * 512;
    vld[i] = idx < nf4;
    int ii = vld[i] ? idx : 0;
    int c = ii / rg;
    int rem = ii - c * rg;
    int row = rem / ng4;
    int g = rem - row * ng4;
    goff[i] = c * HW_ + (ymin + row) * W_ + xs4 + 4 * g;
    loff[i] = c * csz + row * S + 4 * g;
  }

  // ---- per-thread fixed compute descriptor ----
  const bool active = tid < NCOMP;
  int o[8]; float wa[8], wb[8];
  int outoff = 0;
  if (active) {
    int c = tid / NBIN;
    int bin = tid - c * NBIN;
    int ph = bin / PW_;
    int pw = bin - ph * PW_;
    float4 ya = yp[ph * 2 + 0], yb = yp[ph * 2 + 1];
    float4 xa = xp[pw * 2 + 0], xb = xp[pw * 2 + 1];
    int r00 = (__float_as_int(ya.x) - ymin) * S;
    int r01 = (__float_as_int(ya.w) - ymin) * S;
    int r10 = (__float_as_int(yb.x) - ymin) * S;
    int r11 = (__float_as_int(yb.w) - ymin) * S;
    int c0 = __float_as_int(xa.x) - xs4;
    int c1 = __float_as_int(xb.x) - xs4;
    int lb = c * csz;
    o[0] = lb + r00 + c0; wa[0] = ya.y * xa.y; wb[0] = ya.y * xa.z;
    o[1] = lb + r01 + c0; wa[1] = ya.z * xa.y; wb[1] = ya.z * xa.z;
    o[2] = lb + r00 + c1; wa[2] = ya.y * xb.y; wb[2] = ya.y * xb.z;
    o[3] = lb + r01 + c1; wa[3] = ya.z * xb.y; wb[3] = ya.z * xb.z;
    o[4] = lb + r10 + c0; wa[4] = yb.y * xa.y; wb[4] = yb.y * xa.z;
    o[5] = lb + r11 + c0; wa[5] = yb.z * xa.y; wb[5] = yb.z * xa.z;
    o[6] = lb + r10 + c1; wa[6] = yb.y * xb.y; wb[6] = yb.y * xb.z;
    o[7] = lb + r11 + c1; wa[7] = yb.z * xb.y; wb[7] = yb.z * xb.z;
    outoff = c * NBIN + bin;
  }

  float* outn = out + (size_t)n * (C_ * NBIN);
  const float* fb = feat + (size_t)base;

  // ---- prologue: issue loads for tile 0 ----
  float4 v[NSTG];
#pragma unroll
  for (int i = 0; i < NSTG; ++i)
    if (vld[i]) v[i] = *(const float4*)(fb + goff[i]);

  for (int ct = 0; ct < NT; ++ct) {
    __syncthreads();   // (A) prev compute done reading LDS; prefetched loads drained here
#pragma unroll
    for (int i = 0; i < NSTG; ++i)
      if (vld[i]) *(float4*)&tile[loff[i]] = v[i];
    __syncthreads();   // (B) tile visible

    // prefetch tile ct+1 — issued here so it stays in flight across the
    // whole compute phase and is only waited on at next iteration's (A)
    if (ct + 1 < NT) {
      const float* fn = fb + (size_t)(ct + 1) * (CT * HW_);
#pragma unroll
      for (int i = 0; i < NSTG; ++i)
        if (vld[i]) v[i] = *(const float4*)(fn + goff[i]);
    }

    if (active) {
      float acc = 0.0f;
#pragma unroll
      for (int q = 0; q < 8; ++q) {
        acc = fmaf(wa[q], tile[o[q]], acc);
        acc = fmaf(wb[q], tile[o[q] + 1], acc);
      }
      outn[ct * NCOMP + outoff] = acc;
    }
  }
}

extern "C" void kernel_launch(void* const* d_in, const int* in_sizes, int n_in,
                              void* d_out, int out_size, void* d_ws, size_t ws_size,
                              hipStream_t stream) {
  const float* feat = (const float*)d_in[0];
  const float* rois = (const float*)d_in[1];
  float* out = (float*)d_out;
  int N = in_sizes[1] / 5;  // rois is (N,5)
  roialign_kernel<<<dim3(N), dim3(512), 0, stream>>>(feat, rois, out);
}

// Round 5
// 258.723 us; speedup vs baseline: 1.5537x; 1.5537x over previous
//
#include <hip/hip_runtime.h>
#include <stdint.h>

#define PH_ 7
#define PW_ 7
#define C_ 256
#define H_ 200
#define W_ 272
#define HW_ (H_*W_)
#define NBIN (PH_*PW_)        // 49
#define SLICE_F4 296          // float4 slots per wave slice (>=288 worst case)
#define MAXE (4*C_*HW_)       // total feature elements

typedef __attribute__((address_space(1))) const void glb_v;
typedef __attribute__((address_space(3))) void lds_v;

__global__ __launch_bounds__(256, 8)
void roialign_kernel(const float* __restrict__ feat,
                     const float* __restrict__ rois,
                     float* __restrict__ out) {
  // yp[2*ph+iy] = {int y0, hy*vy, ly*vy, int y1i}
  // xp[2*pw+ix] = {int c,  wl,    wr,    0}   (weights fold vx*0.25, edge-clamped)
  __shared__ float4 yp[PH_*2];
  __shared__ float4 xp[PW_*2];
  __shared__ int prm[5];   // base, ymin, xs4, rh, ng4
  __shared__ __align__(16) float4 tile[4 * SLICE_F4];   // 18.9 KB, one slice per wave

  const int n = blockIdx.x;
  const int tid = threadIdx.x;
  const int lane = tid & 63;
  const int wid = tid >> 6;
  const float* roi = rois + (size_t)n * 5;

  if (tid < 28) {
    float x1 = roi[1] * 0.0625f, y1 = roi[2] * 0.0625f;
    float x2 = roi[3] * 0.0625f, y2 = roi[4] * 0.0625f;
    float roi_w = fmaxf(x2 - x1, 1.0f);
    float roi_h = fmaxf(y2 - y1, 1.0f);
    float bin_w = roi_w * (1.0f / 7.0f);
    float bin_h = roi_h * (1.0f / 7.0f);
    if (tid == 0) prm[0] = (int)roi[0] * (C_ * HW_);
    if (tid < 14) {
      int ph = tid >> 1, iy = tid & 1;
      float y = y1 + (float)ph * bin_h + ((float)iy + 0.5f) * bin_h * 0.5f;
      float v = (y >= -1.0f && y <= (float)H_) ? 1.0f : 0.0f;
      float yc = fminf(fmaxf(y, 0.0f), (float)(H_ - 1));
      int y0 = (int)floorf(yc);
      if (y0 > H_ - 1) y0 = H_ - 1;
      int y1i = min(y0 + 1, H_ - 1);
      float ly = yc - (float)y0;
      float hy = 1.0f - ly;
      yp[tid] = make_float4(__int_as_float(y0), hy * v, ly * v,
                            __int_as_float(y1i));
    } else {
      int t = tid - 14;
      int pw = t >> 1, ix = t & 1;
      float x = x1 + (float)pw * bin_w + ((float)ix + 0.5f) * bin_w * 0.5f;
      float v = (x >= -1.0f && x <= (float)W_) ? 0.25f : 0.0f;
      float xc = fminf(fmaxf(x, 0.0f), (float)(W_ - 1));
      int x0 = (int)floorf(xc);
      float lx = xc - (float)x0;
      float hx = 1.0f - lx;
      int c; float wl, wr;
      if (x0 >= W_ - 1) { c = W_ - 2; wl = 0.0f; wr = hx * v; }
      else              { c = x0;     wl = hx * v; wr = lx * v; }
      xp[t] = make_float4(__int_as_float(c), wl, wr, 0.0f);
    }
  }
  __syncthreads();

  if (tid == 0) {
    int ymin = H_, ymax = 0, cmin = W_, cmax = 0;
#pragma unroll
    for (int i = 0; i < 14; ++i) {
      int y0 = __float_as_int(yp[i].x), y1i = __float_as_int(yp[i].w);
      ymin = min(ymin, y0); ymax = max(ymax, y1i);
      int c = __float_as_int(xp[i].x);
      cmin = min(cmin, c); cmax = max(cmax, c);
    }
    int xs4 = cmin & ~3;
    prm[1] = ymin;
    prm[2] = xs4;
    prm[3] = ymax - ymin + 1;              // rh <= 32
    prm[4] = (cmax + 5 - xs4) >> 2;        // ng4 <= 9 (covers col cmax+1)
  }
  __syncthreads();

  const int base = prm[0];
  const int ymin = prm[1];
  const int xs4  = prm[2];
  const int rh   = prm[3];
  const int ng4  = prm[4];
  const int nf4  = rh * ng4;        // float4s per channel (<=288)
  const int S4   = 4 * ng4;         // packed row stride (elements)

  // ---- staging descriptors: idx = lane + 64*i -> LDS float4 slot idx (linear).
  // Rotation swizzle on the SOURCE: slot (row,p) holds source group g=(p-row)%ng4.
  int goff[5];
  bool vld[5];
#pragma unroll
  for (int i = 0; i < 5; ++i) {
    int idx = lane + 64 * i;
    vld[i] = idx < nf4;
    int ii = vld[i] ? idx : 0;
    int row = ii / ng4;
    int p = ii - row * ng4;
    int g = p - row % ng4;
    if (g < 0) g += ng4;
    goff[i] = (ymin + row) * W_ + xs4 + 4 * g;
  }

  // ---- compute descriptors: 16 taps, ROI-constant element offsets into tile ----
  const bool act = lane < NBIN;
  int a16[16];
  float w16[16];
  {
    int bin = act ? lane : 0;
    int ph = bin / PW_;
    int pw = bin - ph * PW_;
    float4 ya = yp[2 * ph], yb2 = yp[2 * ph + 1];
    float4 xa = xp[2 * pw], xb2 = xp[2 * pw + 1];
    int rowv[4] = {__float_as_int(ya.x), __float_as_int(ya.w),
                   __float_as_int(yb2.x), __float_as_int(yb2.w)};
    float wy[4] = {ya.y, ya.z, yb2.y, yb2.z};
    int colv[4] = {__float_as_int(xa.x), __float_as_int(xa.x) + 1,
                   __float_as_int(xb2.x), __float_as_int(xb2.x) + 1};
    float wx[4] = {xa.y, xa.z, xb2.y, xb2.z};
    int lbase = wid * (SLICE_F4 * 4);   // slice base in floats
#pragma unroll
    for (int r = 0; r < 4; ++r) {
      int rr = rowv[r] - ymin;
      int rm = rr % ng4;
#pragma unroll
      for (int c2 = 0; c2 < 4; ++c2) {
        int crel = colv[c2] - xs4;
        int g0 = crel >> 2, c3 = crel & 3;
        int p = g0 + rm;
        if (p >= ng4) p -= ng4;          // rotated group position
        a16[r * 4 + c2] = lbase + rr * S4 + p * 4 + c3;
        w16[r * 4 + c2] = wy[r] * wx[c2];
      }
    }
  }

  const float* fptr = feat + (size_t)base + (size_t)wid * HW_;
  float* optr = out + (size_t)n * (C_ * NBIN) + wid * NBIN + lane;
  const float* tf = (const float*)tile;
  char* ldsb = (char*)tile + wid * (SLICE_F4 * 16);
  const float* fend = feat + (MAXE - 4);

  // ---- barrier-free per-wave channel loop: wave wid handles c = 4j+wid ----
  for (int j = 0; j < 64; ++j) {
#pragma unroll
    for (int i = 0; i < 5; ++i) {
      if (vld[i]) {
        const float* src = fptr + goff[i];
        if (src > fend) src = fend;      // tail clamp (only garbage cols affected)
        __builtin_amdgcn_global_load_lds((glb_v*)src, (lds_v*)(ldsb + i * 1024),
                                         16, 0, 0);
      }
    }
    asm volatile("s_waitcnt vmcnt(0)" ::: "memory");   // slice populated
    if (act) {
      float acc = 0.0f;
#pragma unroll
      for (int q = 0; q < 16; ++q) acc = fmaf(w16[q], tf[a16[q]], acc);
      *optr = acc;
    }
    asm volatile("s_waitcnt lgkmcnt(0)" ::: "memory"); // reads drained before overwrite
    fptr += 4 * HW_;
    optr += 4 * NBIN;
  }
}

extern "C" void kernel_launch(void* const* d_in, const int* in_sizes, int n_in,
                              void* d_out, int out_size, void* d_ws, size_t ws_size,
                              hipStream_t stream) {
  const float* feat = (const float*)d_in[0];
  const float* rois = (const float*)d_in[1];
  float* out = (float*)d_out;
  int N = in_sizes[1] / 5;  // rois is (N,5)
  roialign_kernel<<<dim3(N), dim3(256), 0, stream>>>(feat, rois, out);
}